// Round 25
// 1583.769 us; speedup vs baseline: 1.2162x; 1.0169x over previous
//
#include <hip/hip_runtime.h>
#include <hip/hip_bf16.h>

#define NR 5000
#define EE 150000
#define NA14 (NR*14)
#define EPSF 1e-8f

typedef unsigned short ushort;
typedef __attribute__((ext_vector_type(8))) short bf16x8;
typedef __attribute__((ext_vector_type(4))) float f32x4;

#define GLDS16(gp, lp) __builtin_amdgcn_global_load_lds( \
    (__attribute__((address_space(1))) void*)(gp), \
    (__attribute__((address_space(3))) void*)(lp), 16, 0, 0)

static __device__ __forceinline__ float wsum64(float v) {
#pragma unroll
  for (int o = 1; o < 64; o <<= 1) v += __shfl_xor(v, o, 64);
  return v;
}
static __device__ __forceinline__ ushort f2b(float f) {
  union { float f; unsigned u; } x; x.f = f;
  unsigned r = (x.u + 0x7FFF + ((x.u >> 16) & 1)) >> 16;
  return (ushort)r;
}
static __device__ __forceinline__ float b2f(ushort b) {
  union { unsigned u; float f; } y; y.u = ((unsigned)b) << 16;
  return y.f;
}
static __device__ __forceinline__ float blo(unsigned u) {
  union { unsigned x; float f; } y; y.x = u << 16; return y.f;
}
static __device__ __forceinline__ float bhi(unsigned u) {
  union { unsigned x; float f; } y; y.x = u & 0xFFFF0000u; return y.f;
}

// ======================= prep kernels =======================

__global__ void k_dihedral(const float* __restrict__ atom14, float* __restrict__ Dp) {
  int i = blockIdx.x * 256 + threadIdx.x;
  const int M3 = 3 * NR;
  if (i >= M3) return;
  if (i == 0 || i >= M3 - 2) { Dp[i] = 0.f; return; }
  int d = i - 1;
  float X[4][3];
#pragma unroll
  for (int t = 0; t < 4; ++t) {
    int j = d + t;
    const float* p = atom14 + (j / 3) * 42 + (j % 3) * 3;
    X[t][0] = p[0]; X[t][1] = p[1]; X[t][2] = p[2];
  }
  float U[3][3];
#pragma unroll
  for (int t = 0; t < 3; ++t) {
    float dx = X[t+1][0]-X[t][0], dy = X[t+1][1]-X[t][1], dz = X[t+1][2]-X[t][2];
    float nr = sqrtf(dx*dx + dy*dy + dz*dz) + EPSF;
    U[t][0] = dx/nr; U[t][1] = dy/nr; U[t][2] = dz/nr;
  }
  float n2[3], n1[3];
  n2[0] = U[0][1]*U[1][2] - U[0][2]*U[1][1];
  n2[1] = U[0][2]*U[1][0] - U[0][0]*U[1][2];
  n2[2] = U[0][0]*U[1][1] - U[0][1]*U[1][0];
  float nn2 = sqrtf(n2[0]*n2[0]+n2[1]*n2[1]+n2[2]*n2[2]) + EPSF;
  n2[0]/=nn2; n2[1]/=nn2; n2[2]/=nn2;
  n1[0] = U[1][1]*U[2][2] - U[1][2]*U[2][1];
  n1[1] = U[1][2]*U[2][0] - U[1][0]*U[2][2];
  n1[2] = U[1][0]*U[2][1] - U[1][1]*U[2][0];
  float nn1 = sqrtf(n1[0]*n1[0]+n1[1]*n1[1]+n1[2]*n1[2]) + EPSF;
  n1[0]/=nn1; n1[1]/=nn1; n1[2]/=nn1;
  float cosD = n2[0]*n1[0]+n2[1]*n1[1]+n2[2]*n1[2];
  cosD = fminf(fmaxf(cosD, -1.f + 1e-7f), 1.f - 1e-7f);
  float sg = U[0][0]*n1[0]+U[0][1]*n1[1]+U[0][2]*n1[2];
  float sgn = (sg > 0.f) ? 1.f : ((sg < 0.f) ? -1.f : 0.f);
  Dp[i] = sgn * acosf(cosD);
}

// bb4/bbl + resf (absorbed k_masks)
__global__ void k_bb4(const float* __restrict__ atom14, const float* __restrict__ rot,
                      const float* __restrict__ trans, const int* __restrict__ rmask,
                      float* __restrict__ bb4, float* __restrict__ bbl,
                      float* __restrict__ resf) {
  int n = blockIdx.x * 256 + threadIdx.x;
  if (n >= NR) return;
  resf[n] = rmask[n] ? 1.f : 0.f;
  const float* a = atom14 + (size_t)n * 42;
  float P[4][3];
#pragma unroll
  for (int c = 0; c < 3; ++c) { P[0][c]=a[c]; P[1][c]=a[3+c]; P[2][c]=a[6+c]; }
  float b[3], cc[3], cr[3];
#pragma unroll
  for (int c = 0; c < 3; ++c) { b[c]=P[1][c]-P[0][c]; cc[c]=P[2][c]-P[1][c]; }
  cr[0]=b[1]*cc[2]-b[2]*cc[1]; cr[1]=b[2]*cc[0]-b[0]*cc[2]; cr[2]=b[0]*cc[1]-b[1]*cc[0];
#pragma unroll
  for (int c = 0; c < 3; ++c)
    P[3][c] = -0.58273431f*cr[c] + 0.56802827f*b[c] - 0.54067466f*cc[c] + P[1][c];
  const float* R = rot + (size_t)n*9;
  const float* t = trans + (size_t)n*3;
#pragma unroll
  for (int p = 0; p < 4; ++p)
#pragma unroll
    for (int i = 0; i < 3; ++i)
      bb4[(size_t)n*12 + p*3 + i] = P[p][i];
#pragma unroll
  for (int p = 0; p < 4; ++p) {
    float d0 = P[p][0]-t[0], d1 = P[p][1]-t[1], d2 = P[p][2]-t[2];
#pragma unroll
    for (int i = 0; i < 3; ++i)
      bbl[(size_t)n*12 + p*3 + i] = R[0*3+i]*d0 + R[1*3+i]*d1 + R[2*3+i]*d2;
  }
}

// node raw features -> bf16 rows of width 64 (K padded from 40)
__global__ void k_noderaw(const int* __restrict__ seq, const float* __restrict__ atom14,
                          const float* __restrict__ rot, const float* __restrict__ trans,
                          const float* __restrict__ Dp, const int* __restrict__ rmask,
                          const int* __restrict__ mgm, ushort* __restrict__ nrawb) {
  int n = blockIdx.x;
  int c = threadIdx.x;   // 64
  float v = 0.f;
  if (c < 40) {
    float mg = mgm[n] ? 1.f : 0.f;
    float rf = rmask[n] ? 1.f : 0.f;
    if (c < 6) {
      float D = Dp[3*n + (c % 3)];
      v = (c < 3) ? cosf(D) : sinf(D);
    } else if (c == 6) v = mg;
    else if (c < 28) v = (seq[n] == c - 7) ? mg : 0.f;
    else {
      int u = c - 28; int p = u / 3, i = u - p*3;
      const float* R = rot + (size_t)n*9;
      const float* t = trans + (size_t)n*3;
      const float* a = atom14 + (size_t)n*42 + p*3;
      v = R[0*3+i]*(a[0]-t[0]) + R[1*3+i]*(a[1]-t[1]) + R[2*3+i]*(a[2]-t[2]);
    }
    v *= rf;
  }
  nrawb[(size_t)n*64 + c] = f2b(v);
}

__global__ void k_atomraw(const int* __restrict__ seq, const int* __restrict__ mgm,
                          const int* __restrict__ a14ex, const float* __restrict__ atab,
                          float* __restrict__ araw, float* __restrict__ amf) {
  int idx = blockIdx.x * 256 + threadIdx.x;
  if (idx >= NA14) return;
  int n = idx / 14, a = idx - n*14;
  float mg = mgm[n] ? 1.f : 0.f;
  float sc = (a >= 4) ? mg : 1.f;
  const float* src = atab + ((size_t)seq[n]*14 + a) * 9;
#pragma unroll
  for (int j = 0; j < 9; ++j) araw[(size_t)idx*9 + j] = src[j] * sc;
  amf[idx] = (a >= 4) ? mg : (a14ex[idx] ? 1.f : 0.f);
}

// edge raw: 16 distances once in lanes 0-15, shfl-broadcast
__global__ void k_edgeraw(const int* __restrict__ dsti, const int* __restrict__ srci,
                          const int* __restrict__ seq, const int* __restrict__ rmask,
                          const int* __restrict__ nmask, const float* __restrict__ bb4,
                          const float* __restrict__ bbl, const float* __restrict__ rot,
                          const float* __restrict__ trans, ushort* __restrict__ eraw,
                          float* __restrict__ emf, int e0, int cnt) {
  int ei = blockIdx.x * 4 + (threadIdx.x >> 6);
  if (ei >= cnt) return;
  int e = e0 + ei;
  int l = threadIdx.x & 63;
  int d = dsti[e], s = srci[e];
  float em = (rmask[d] && rmask[s]) ? 1.f : 0.f;
  if (l == 0) emf[e] = em;
  float ns = nmask[s] ? 1.f : 0.f;
  float nd = nmask[d] ? 1.f : 0.f;
  ushort* out = eraw + (size_t)ei * 352;

  float dist;
  {
    int p = (l >> 2) & 3, q = l & 3;
    const float* Ps = bb4 + (size_t)s*12 + p*3;
    const float* Pd = bb4 + (size_t)d*12 + q*3;
    float dx = Ps[0]-Pd[0]+EPSF, dy = Ps[1]-Pd[1]+EPSF, dz = Ps[2]-Pd[2]+EPSF;
    dist = sqrtf(dx*dx + dy*dy + dz*dz);
  }
  {
    int q = (l >> 4) & 3;
    float mu = 2.f + (20.f / 15.f) * (float)(l & 15);
#pragma unroll
    for (int p = 0; p < 4; ++p) {
      float dd = __shfl(dist, p*4 + q, 64);
      float tt = (dd - mu) * 0.8f;
      out[44 + p*64 + l] = f2b(expf(-tt * tt) * em);
    }
  }
  if (l < 44) {
    float v;
    if (l == 0) v = nd;
    else if (l == 1) v = ns;
    else if (l < 23) v = (seq[s] == l - 2) ? (1.f - ns) : 0.f;
    else v = (seq[d] == l - 23) ? (1.f - nd) : 0.f;
    out[l] = f2b(v * em);
  }
  if (l < 52) {
    int c = 300 + l;
    float v;
    if (c < 316) {
      int f = c - 300;
      int j = (f < 8) ? f : (f - 8);
      float freq = expf((float)(2*j) * (-9.210340371976184f / 16.f));
      float ang = (float)(d - s) * freq;
      v = (f < 8) ? cosf(ang) : sinf(ang);
    } else if (c < 328) {
      v = bbl[(size_t)s*12 + (c - 316)] * (1.f - ns);
    } else if (c < 340) {
      int u = c - 328; int p = u / 3, i = u - p*3;
      const float* R = rot + (size_t)s*9;
      const float* t = trans + (size_t)s*3;
      const float* Pd = bb4 + (size_t)d*12 + p*3;
      v = (R[0*3+i]*(Pd[0]-t[0]) + R[1*3+i]*(Pd[1]-t[1]) + R[2*3+i]*(Pd[2]-t[2])) * (1.f - nd);
    } else v = 0.f;
    out[c] = f2b(v * em);
  }
}

// ======================= CSR build =======================

__global__ void k_zero_int(int* __restrict__ p, int n) {
  int i = blockIdx.x * 256 + threadIdx.x;
  if (i < n) p[i] = 0;
}
__global__ void k_count(const int* __restrict__ dsti, int* __restrict__ cnt) {
  int e = blockIdx.x * 256 + threadIdx.x;
  if (e < EE) atomicAdd(&cnt[dsti[e]], 1);
}
__global__ void k_scan(const int* __restrict__ cnt, int* __restrict__ offs) {
  __shared__ int part[257];
  int t = threadIdx.x;
  const int chunk = (NR + 255) / 256;
  int b = t * chunk;
  int e = min(b + chunk, NR);
  int s = 0;
  for (int i = b; i < e; ++i) s += cnt[i];
  part[t] = s;
  __syncthreads();
  if (t == 0) {
    int r = 0;
    for (int i = 0; i < 256; ++i) { int c = part[i]; part[i] = r; r += c; }
    part[256] = r;
  }
  __syncthreads();
  int r = part[t];
  for (int i = b; i < e; ++i) { offs[i] = r; r += cnt[i]; }
  if (t == 0) offs[NR] = part[256];
}
__global__ void k_place(const int* __restrict__ dsti, const int* __restrict__ offs,
                        int* __restrict__ cnt, int* __restrict__ eord) {
  int e = blockIdx.x * 256 + threadIdx.x;
  if (e < EE) {
    int d = dsti[e];
    int pos = offs[d] + atomicAdd(&cnt[d], 1);
    eord[pos] = e;
  }
}
__global__ void k_sortwave(const int* __restrict__ offs, int* __restrict__ eord) {
  int n = blockIdx.x;
  int l = threadIdx.x;
  int b = offs[n], e = offs[n+1];
  int deg = e - b;
  if (deg <= 1) return;
  if (deg <= 64) {
    int v = (l < deg) ? eord[b + l] : 0x7FFFFFFF;
#pragma unroll
    for (int k = 2; k <= 64; k <<= 1) {
#pragma unroll
      for (int j = k >> 1; j > 0; j >>= 1) {
        int o = __shfl_xor(v, j, 64);
        bool up = ((l & k) == 0);
        bool first = ((l & j) == 0);
        int mn = min(v, o), mx = max(v, o);
        v = (first == up) ? mn : mx;
      }
    }
    if (l < deg) eord[b + l] = v;
  } else if (l == 0) {
    for (int i = b + 1; i < e; ++i) {
      int key = eord[i]; int j = i - 1;
      while (j >= b && eord[j] > key) { eord[j+1] = eord[j]; --j; }
      eord[j+1] = key;
    }
  }
}

// ===== weight transpose f32(K,N)->bf16(N,Kpad), L layers strided.
// cperm: permute output columns n_src = (n>>2) + (n&3)*64 (V interleave)
__global__ void k_wT(const float* __restrict__ W, ushort* __restrict__ WT,
                     int K, int N, int Kpad, long sstride, long dstride, int L,
                     int perm, int cperm) {
  long idx = (long)blockIdx.x * 256 + threadIdx.x;
  long per = (long)N * Kpad;
  if (idx >= per * L) return;
  int l = (int)(idx / per); long r = idx - (long)l * per;
  int n = (int)(r / Kpad), k = (int)(r - (long)n * Kpad);
  int ks = perm ? ((k & ~63) | ((k & 3) * 16 + ((k >> 2) & 15))) : k;
  int ns = cperm ? ((n >> 2) + (n & 3) * 64) : n;
  WT[(size_t)l * dstride + (size_t)n * Kpad + k] =
      (ks < K) ? f2b(W[(size_t)l * sstride + (size_t)ks * N + ns]) : (ushort)0;
}

__global__ void k_zero_us(ushort* __restrict__ p, int per, long stride, int L) {
  long idx = (long)blockIdx.x * 256 + threadIdx.x;
  if (idx >= (long)per * L) return;
  int l = (int)(idx / per); int r = (int)(idx - (long)l * per);
  p[(size_t)l * stride + r] = 0;
}

// WbT[l][h][dim] = Wb[l][dim][h]
__global__ void k_wbT(const float* __restrict__ Wb, float* __restrict__ WbT) {
  int idx = blockIdx.x * 256 + threadIdx.x;
  if (idx >= 2048) return;
  int l = idx >> 9; int r = idx & 511; int h = r >> 7; int dim = r & 127;
  WbT[idx] = Wb[(size_t)l * 512 + dim * 4 + h];
}
__global__ void k_coef(const float* __restrict__ gam, float* __restrict__ coef) {
  int i = threadIdx.x;
  if (i < 16) coef[i] = 0.5f * (1.f / 6.f) * log1pf(expf(gam[i]));
}

// ======================= MFMA bf16 GEMM =======================
// LNZ (requires Ncols==128): fused per-row LayerNorm epilogue.
// hstride: row stride (elements) of HD/HS gather tables (EPADD only).
// SPLIT: cols >= 768 go to Cf as f32 with stride 256 (QKV|PP merged gemm).
template<int RELU, int OUTBF, int EPADD, int PERMOUT, int LNZ, int SPLIT>
__global__ __launch_bounds__(256) void k_mgemm(
    const ushort* __restrict__ A, const ushort* __restrict__ BT,
    float* __restrict__ Cf, ushort* __restrict__ Cb,
    int M, int Ncols, int Kd, int lda,
    const ushort* __restrict__ HD, const ushort* __restrict__ HS,
    const int* __restrict__ dsti, const int* __restrict__ srci,
    const float* __restrict__ lnsc, int hstride) {
  __shared__ __align__(16) ushort As[2][128][4][8];
  __shared__ __align__(16) ushort Bs[2][128][4][8];
  const int tid = threadIdx.x;
  const int lane = tid & 63;
  const int w = tid >> 6;
  const int wm = (w >> 1) * 64;
  const int wn = (w & 1) * 64;
  const int bm = blockIdx.x * 128;
  const int bn = blockIdx.y * 128;
  const int rl0 = tid >> 2;
  const int sl  = tid & 3;
  const int rl1 = rl0 + 64;
  const int ks0 = (sl - rl0 - (rl0 >> 2)) & 3;
  const int ks1 = (sl - rl1 - (rl1 >> 2)) & 3;
  int ar0 = bm + rl0; if (ar0 >= M) ar0 = M - 1;
  int ar1 = bm + rl1; if (ar1 >= M) ar1 = M - 1;
  const ushort* gA0 = A + (size_t)ar0 * lda + ks0 * 8;
  const ushort* gA1 = A + (size_t)ar1 * lda + ks1 * 8;
  const ushort* gB0 = BT + (size_t)(bn + rl0) * Kd + ks0 * 8;
  const ushort* gB1 = BT + (size_t)(bn + rl1) * Kd + ks1 * 8;

  auto stage = [&](int buf, int k0) {
    GLDS16(gA0 + k0, &As[buf][rl0][sl][0]);
    GLDS16(gB0 + k0, &Bs[buf][rl0][sl][0]);
    GLDS16(gA1 + k0, &As[buf][rl1][sl][0]);
    GLDS16(gB1 + k0, &Bs[buf][rl1][sl][0]);
  };

  f32x4 zero4 = {0.f, 0.f, 0.f, 0.f};
  f32x4 acc[4][4];
#pragma unroll
  for (int i = 0; i < 4; ++i)
#pragma unroll
    for (int j = 0; j < 4; ++j) acc[i][j] = zero4;

  stage(0, 0);
  asm volatile("s_waitcnt vmcnt(0)" ::: "memory");
  __builtin_amdgcn_s_barrier();

  const int nt = Kd >> 5;
  for (int t = 0; t < nt; ++t) {
    int cur = t & 1;
    if (t + 1 < nt) stage(cur ^ 1, (t + 1) << 5);
    {
      const int ksr = lane >> 4, lr = lane & 15;
      bf16x8 af[4], bf[4];
#pragma unroll
      for (int i = 0; i < 4; ++i) {
        int row = wm + i*16 + lr;
        int sa = (ksr + row + (row >> 2)) & 3;
        af[i] = *reinterpret_cast<const bf16x8*>(&As[cur][row][sa][0]);
      }
#pragma unroll
      for (int j = 0; j < 4; ++j) {
        int col = wn + j*16 + lr;
        int sb = (ksr + col + (col >> 2)) & 3;
        bf[j] = *reinterpret_cast<const bf16x8*>(&Bs[cur][col][sb][0]);
      }
#pragma unroll
      for (int i = 0; i < 4; ++i)
#pragma unroll
        for (int j = 0; j < 4; ++j)
          acc[i][j] = __builtin_amdgcn_mfma_f32_16x16x32_bf16(af[i], bf[j], acc[i][j], 0, 0, 0);
    }
    asm volatile("s_waitcnt vmcnt(0) lgkmcnt(0)" ::: "memory");
    __builtin_amdgcn_s_barrier();
  }

  int lr = lane & 15, lg = lane >> 4;
  if (LNZ) {
    float* stats = (float*)As;   // 512 floats (As dead)
#pragma unroll
    for (int i = 0; i < 4; ++i) {
#pragma unroll
      for (int rg = 0; rg < 4; ++rg) {
        float ps = 0.f, pq = 0.f;
#pragma unroll
        for (int j = 0; j < 4; ++j) {
          float v = b2f(f2b(acc[i][j][rg]));
          ps += v; pq += v * v;
        }
#pragma unroll
        for (int o = 1; o < 16; o <<= 1) {
          ps += __shfl_xor(ps, o, 64);
          pq += __shfl_xor(pq, o, 64);
        }
        if (lr == 0) {
          int row = wm + i*16 + lg*4 + rg;
          stats[(row * 2 + (wn >> 6)) * 2 + 0] = ps;
          stats[(row * 2 + (wn >> 6)) * 2 + 1] = pq;
        }
      }
    }
    __syncthreads();
#pragma unroll
    for (int i = 0; i < 4; ++i) {
#pragma unroll
      for (int rg = 0; rg < 4; ++rg) {
        int row = wm + i*16 + lg*4 + rg;
        int m = bm + row;
        float s0 = stats[(row*2 + 0)*2 + 0] + stats[(row*2 + 1)*2 + 0];
        float q0 = stats[(row*2 + 0)*2 + 1] + stats[(row*2 + 1)*2 + 1];
        float mu = s0 * (1.f / 128.f);
        float var = q0 * (1.f / 128.f) - mu * mu;
        float rs = rsqrtf(var + 1e-5f);
        if (m < M) {
          float sc = lnsc ? lnsc[m] : 1.f;
#pragma unroll
          for (int j = 0; j < 4; ++j) {
            int cc = wn + j*16 + lr;
            float v = b2f(f2b(acc[i][j][rg]));
            Cb[(size_t)m * 128 + cc] = f2b((v - mu) * rs * sc);
          }
        }
      }
    }
  } else if (PERMOUT) {
    const int pc = bn + wn + lr * 4;
    uint2 hd[4][4], hs[4][4];
    if (EPADD) {
      // batch all 32 gathers (independent; overlap L2 latency)
#pragma unroll
      for (int i = 0; i < 4; ++i) {
#pragma unroll
        for (int rg = 0; rg < 4; ++rg) {
          int m = bm + wm + i*16 + lg*4 + rg;
          int mc = (m < M) ? m : (M - 1);
          int de = dsti[mc], se = srci[mc];
          hd[i][rg] = *reinterpret_cast<const uint2*>(HD + (size_t)de * hstride + pc);
          hs[i][rg] = *reinterpret_cast<const uint2*>(HS + (size_t)se * hstride + pc);
        }
      }
    }
#pragma unroll
    for (int i = 0; i < 4; ++i) {
#pragma unroll
      for (int rg = 0; rg < 4; ++rg) {
        int m = bm + wm + i*16 + lg*4 + rg;
        if (m >= M) continue;
        float v0 = acc[i][0][rg], v1 = acc[i][1][rg];
        float v2 = acc[i][2][rg], v3 = acc[i][3][rg];
        if (EPADD) {
          v0 += blo(hd[i][rg].x) + blo(hs[i][rg].x);
          v1 += bhi(hd[i][rg].x) + bhi(hs[i][rg].x);
          v2 += blo(hd[i][rg].y) + blo(hs[i][rg].y);
          v3 += bhi(hd[i][rg].y) + bhi(hs[i][rg].y);
        }
        if (RELU) {
          v0 = fmaxf(v0, 0.f); v1 = fmaxf(v1, 0.f);
          v2 = fmaxf(v2, 0.f); v3 = fmaxf(v3, 0.f);
        }
        uint2 p;
        p.x = (unsigned)f2b(v0) | ((unsigned)f2b(v1) << 16);
        p.y = (unsigned)f2b(v2) | ((unsigned)f2b(v3) << 16);
        *reinterpret_cast<uint2*>(Cb + (size_t)m * Ncols + pc) = p;
      }
    }
  } else {
#pragma unroll
    for (int i = 0; i < 4; ++i) {
#pragma unroll
      for (int rg = 0; rg < 4; ++rg) {
        int m = bm + wm + i*16 + lg*4 + rg;
        if (m >= M) continue;
#pragma unroll
        for (int j = 0; j < 4; ++j) {
          int cc = bn + wn + j*16 + lr;
          float v = acc[i][j][rg];
          if (RELU) v = fmaxf(v, 0.f);
          if (SPLIT && bn >= 768) {
            Cf[(size_t)m * 256 + (cc - 768)] = v;
          } else if (OUTBF) {
            Cb[(size_t)m * Ncols + cc] = f2b(v);
          } else {
            Cf[(size_t)m * Ncols + cc] = v;
          }
        }
      }
    }
  }
}

// ======================= f32 GEMM (T1 only) =======================
__global__ void k_gemm(const float* __restrict__ A, const float* __restrict__ B,
                       float* __restrict__ C, int M, int Ncols, int Kd,
                       int ldc, int coff, int relu) {
  __shared__ float As[16][68];
  __shared__ float Bs[16][64];
  const int tid = threadIdx.x;
  const int bm = blockIdx.x * 64;
  const int bn = blockIdx.y * 64;
  const int tm = tid >> 4;
  const int tn = tid & 15;
  const int arow = tid >> 2;
  const int akq = (tid & 3) << 2;
  const int brow = tid >> 4;
  const int bcol = (tid & 15) << 2;
  float acc[4][4] = {{0.f}};
  const int am = bm + arow;
  for (int k0 = 0; k0 < Kd; k0 += 16) {
    float av[4];
#pragma unroll
    for (int j = 0; j < 4; ++j) {
      int k = k0 + akq + j;
      av[j] = (am < M && k < Kd) ? A[(size_t)am * Kd + k] : 0.f;
    }
#pragma unroll
    for (int j = 0; j < 4; ++j) As[akq + j][arow] = av[j];
    int kb = k0 + brow;
    float bv[4];
    if (kb < Kd) {
#pragma unroll
      for (int j = 0; j < 4; ++j) {
        int c = bn + bcol + j;
        bv[j] = (c < Ncols) ? B[(size_t)kb * Ncols + c] : 0.f;
      }
    } else { bv[0]=bv[1]=bv[2]=bv[3]=0.f; }
    *reinterpret_cast<float4*>(&Bs[brow][bcol]) = make_float4(bv[0],bv[1],bv[2],bv[3]);
    __syncthreads();
#pragma unroll
    for (int kk = 0; kk < 16; ++kk) {
      float4 a4 = *reinterpret_cast<const float4*>(&As[kk][tm << 2]);
      float4 b4 = *reinterpret_cast<const float4*>(&Bs[kk][tn << 2]);
      float aa[4] = {a4.x, a4.y, a4.z, a4.w};
      float bb[4] = {b4.x, b4.y, b4.z, b4.w};
#pragma unroll
      for (int i = 0; i < 4; ++i)
#pragma unroll
        for (int j = 0; j < 4; ++j)
          acc[i][j] = fmaf(aa[i], bb[j], acc[i][j]);
    }
    __syncthreads();
  }
#pragma unroll
  for (int i = 0; i < 4; ++i) {
    int m = bm + (tm << 2) + i;
    if (m >= M) continue;
#pragma unroll
    for (int j = 0; j < 4; ++j) {
      int c = bn + (tn << 2) + j;
      if (c >= Ncols) continue;
      float v = acc[i][j];
      if (relu) v = fmaxf(v, 0.f);
      C[(size_t)m * ldc + coff + c] = v;
    }
  }
}

// small-K GEMM (atom MLP)
__global__ void k_small_gemm(const float* __restrict__ A, const float* __restrict__ B,
                             float* __restrict__ C, int M, int Ncols, int Kd, int relu) {
  __shared__ float Ws[1024];
  int t = threadIdx.x;
  int nw = Kd * Ncols;
  for (int i = t; i < nw; i += 256) Ws[i] = B[i];
  __syncthreads();
  int rpb = 256 / Ncols;
  int r = blockIdx.x * rpb + t / Ncols;
  int c = t - (t / Ncols) * Ncols;
  if (r >= M || t >= rpb * Ncols) return;
  const float* a = A + (size_t)r * Kd;
  float s = 0.f;
  for (int k = 0; k < Kd; ++k) s = fmaf(a[k], Ws[k * Ncols + c], s);
  if (relu) s = fmaxf(s, 0.f);
  C[(size_t)r * Ncols + c] = s;
}

// ======================= LayerNorm =======================
__global__ void k_ln(float* __restrict__ dst, ushort* __restrict__ dstb,
                     const float* __restrict__ res, const float* __restrict__ x,
                     const float* __restrict__ rowscale, int M) {
  int r = blockIdx.x * 4 + (threadIdx.x >> 6);
  if (r >= M) return;
  int l = threadIdx.x & 63;
  size_t base = (size_t)r * 256 + l * 4;
  float4 v = *reinterpret_cast<const float4*>(x + base);
  if (res) {
    float4 rv = *reinterpret_cast<const float4*>(res + base);
    v.x += rv.x; v.y += rv.y; v.z += rv.z; v.w += rv.w;
  }
  float s = wsum64(v.x + v.y + v.z + v.w);
  float mu = s * (1.f / 256.f);
  float d0 = v.x-mu, d1 = v.y-mu, d2 = v.z-mu, d3 = v.w-mu;
  float s2 = wsum64(d0*d0 + d1*d1 + d2*d2 + d3*d3);
  float rs = rsqrtf(s2 * (1.f / 256.f) + 1e-5f);
  float sc = rowscale ? rowscale[r] : 1.f;
  float o0 = d0*rs*sc, o1 = d1*rs*sc, o2 = d2*rs*sc, o3 = d3*rs*sc;
  *reinterpret_cast<float4*>(dst + base) = make_float4(o0, o1, o2, o3);
  if (dstb) {
    uint2 p;
    p.x = (unsigned)f2b(o0) | ((unsigned)f2b(o1) << 16);
    p.y = (unsigned)f2b(o2) | ((unsigned)f2b(o3) << 16);
    *reinterpret_cast<uint2*>(dstb + base) = p;
  }
}

__global__ void k_ln16(float* __restrict__ af, int M) {
  int r = blockIdx.x * 256 + threadIdx.x;
  if (r >= M) return;
  float x[16]; float s = 0.f;
#pragma unroll
  for (int j = 0; j < 16; ++j) { x[j] = af[(size_t)r*16 + j]; s += x[j]; }
  float mu = s * (1.f/16.f);
  float v = 0.f;
#pragma unroll
  for (int j = 0; j < 16; ++j) { float d = x[j]-mu; v += d*d; }
  float rs = rsqrtf(v * (1.f/16.f) + 1e-5f);
#pragma unroll
  for (int j = 0; j < 16; ++j) af[(size_t)r*16 + j] = (x[j]-mu)*rs;
}

// ======================= layer kernels =======================

__global__ void k_qg(const float* __restrict__ rot, const float* __restrict__ trans,
                     const float* __restrict__ pp,
                     float* __restrict__ qg, float* __restrict__ kg) {
  int idx = blockIdx.x * 256 + threadIdx.x;
  if (idx >= NR * 64) return;
  int n = idx >> 6; int w = (idx >> 5) & 1; int hp = idx & 31;
  const float* src = pp + (size_t)n*256 + (w ? 96 : 0) + hp*3;
  float* dstp = (w ? kg : qg) + (size_t)n*96 + hp*3;
  const float* R = rot + (size_t)n*9;
  const float* t = trans + (size_t)n*3;
  float s0 = src[0], s1 = src[1], s2 = src[2];
#pragma unroll
  for (int i = 0; i < 3; ++i)
    dstp[i] = R[i*3+0]*s0 + R[i*3+1]*s1 + R[i*3+2]*s2 + t[i];
}

// fused logits + online-softmax attention + olon epilogue:
// 1 node per 256-thread block, 4 waves (stride-4 edge split) with LDS merge.
// Lane-parallel index prefetch + manual software pipeline of gathers.
// V stored column-interleaved (c -> (c&63)*4+(c>>6)) so one uint2 load
// fetches lane l's 4 head values.
__global__ __launch_bounds__(256) void k_attn2(
    const int* __restrict__ offs, const int* __restrict__ eord,
    const int* __restrict__ srci, const float* __restrict__ emf,
    const ushort* __restrict__ qkv, const ushort* __restrict__ z,
    const float* __restrict__ qg, const float* __restrict__ kg,
    const float* __restrict__ WbT, const float* __restrict__ coef,
    const float* __restrict__ rot, const float* __restrict__ trans,
    ushort* __restrict__ catb) {
  __shared__ float MS[4][8];          // [qtr][{m[4],den[4]}]
  __shared__ float AV[4][4][64];
  __shared__ float AG0[4][64];
  __shared__ float AG1[4][32];
  __shared__ float OGm[96];
  const int qtr = threadIdx.x >> 6;
  const int n = blockIdx.x;
  const int l = threadIdx.x & 63;
  const int hh = l >> 4, t = l & 15;
  const int e0 = offs[n], e1 = offs[n+1];
  const float wl = 0.57735026918962576f;
  const float qk_scale = wl * 0.125f;
  // per-node invariants
  uint2 qw = *reinterpret_cast<const uint2*>(qkv + n*768 + hh*64 + t*4);
  float q0 = blo(qw.x), q1 = bhi(qw.x), q2 = blo(qw.y), q3 = bhi(qw.y);
  float qg1 = qg[n*96 + hh*24 + t];
  float qg2 = (t < 8) ? qg[n*96 + hh*24 + t + 16] : 0.f;
  float cf = coef[hh];
  const float* wb = WbT + hh*128 + t*8;
  float4 w0 = *reinterpret_cast<const float4*>(wb);
  float4 w1 = *reinterpret_cast<const float4*>(wb + 4);
  int hg0 = l / 24;
  int hg1 = (64 + l) / 24;

  float m[4] = {-1e30f,-1e30f,-1e30f,-1e30f};
  float den[4] = {0.f,0.f,0.f,0.f};
  float accv[4] = {0.f,0.f,0.f,0.f};
  float acg0 = 0.f, acg1 = 0.f;

  for (int base = e0 + qtr; base < e1; base += 256) {
    // parallel prefetch of indices: lane j covers iteration j of this chunk
    int eL = 0, sL = 0; float emL = 0.f;
    int pidx = base + 4 * l;
    if (pidx < e1) { eL = eord[pidx]; sL = srci[eL]; emL = emf[eL]; }
    int nit = e1 - base; nit = (nit + 3) >> 2; if (nit > 64) nit = 64;
    // ---- preload iteration 0 data ----
    int s_c = __shfl(sL, 0, 64);
    int e_c = __shfl(eL, 0, 64);
    float em_c = __shfl(emL, 0, 64);
    uint2 kw_c = *reinterpret_cast<const uint2*>(qkv + s_c*768 + 256 + hh*64 + t*4);
    uint4 zw_c = *reinterpret_cast<const uint4*>(z + (size_t)e_c*128 + t*8);
    float kq1_c = kg[s_c*96 + hh*24 + t];
    float kq2_c = (t < 8) ? kg[s_c*96 + hh*24 + t + 16] : 0.f;
    uint2 vw_c = *reinterpret_cast<const uint2*>(qkv + s_c*768 + 512 + l*4);
    float g0_c = kg[s_c*96 + l];
    float g1_c = (l < 32) ? kg[s_c*96 + 64 + l] : 0.f;
    for (int it = 0; it < nit; ++it) {
      // ---- issue loads for it+1 (overlap with compute below) ----
      int itn = (it + 1 < nit) ? it + 1 : it;
      int s_n = __shfl(sL, itn, 64);
      int e_n = __shfl(eL, itn, 64);
      float em_n = __shfl(emL, itn, 64);
      uint2 kw_n = *reinterpret_cast<const uint2*>(qkv + s_n*768 + 256 + hh*64 + t*4);
      uint4 zw_n = *reinterpret_cast<const uint4*>(z + (size_t)e_n*128 + t*8);
      float kq1_n = kg[s_n*96 + hh*24 + t];
      float kq2_n = (t < 8) ? kg[s_n*96 + hh*24 + t + 16] : 0.f;
      uint2 vw_n = *reinterpret_cast<const uint2*>(qkv + s_n*768 + 512 + l*4);
      float g0_n = kg[s_n*96 + l];
      float g1_n = (l < 32) ? kg[s_n*96 + 64 + l] : 0.f;
      // ---- logit from current (all registers) ----
      float acc = qk_scale * (q0*blo(kw_c.x) + q1*bhi(kw_c.x) + q2*blo(kw_c.y) + q3*bhi(kw_c.y));
      acc += wl * (blo(zw_c.x)*w0.x + bhi(zw_c.x)*w0.y + blo(zw_c.y)*w0.z + bhi(zw_c.y)*w0.w
                 + blo(zw_c.z)*w1.x + bhi(zw_c.z)*w1.y + blo(zw_c.w)*w1.z + bhi(zw_c.w)*w1.w);
      {
        float dq = qg1 - kq1_c;
        acc -= cf * dq * dq;
        if (t < 8) {
          float dq2 = qg2 - kq2_c;
          acc -= cf * dq2 * dq2;
        }
      }
#pragma unroll
      for (int o = 1; o < 16; o <<= 1) acc += __shfl_xor(acc, o, 64);
      // ---- online softmax update; rare-rescale fast path (wave-uniform) ----
      float lgv[4];
      bool resc = false;
#pragma unroll
      for (int h = 0; h < 4; ++h) {
        float vh = __shfl(acc, h*16, 64);
        lgv[h] = (em_c > 0.f) ? vh : -1e9f;
        if (lgv[h] > m[h]) resc = true;
      }
      if (!resc) {
        float a[4];
#pragma unroll
        for (int h = 0; h < 4; ++h) { a[h] = expf(lgv[h] - m[h]) * em_c; den[h] += a[h]; }
        accv[0] = fmaf(a[0], blo(vw_c.x), accv[0]);
        accv[1] = fmaf(a[1], bhi(vw_c.x), accv[1]);
        accv[2] = fmaf(a[2], blo(vw_c.y), accv[2]);
        accv[3] = fmaf(a[3], bhi(vw_c.y), accv[3]);
        acg0 = fmaf(a[hg0], g0_c, acg0);
        if (l < 32) acg1 = fmaf(a[hg1], g1_c, acg1);
      } else {
        float a[4], r[4];
#pragma unroll
        for (int h = 0; h < 4; ++h) {
          float mn = m[h];
          r[h] = 1.f;
          if (lgv[h] > mn) { r[h] = expf(mn - lgv[h]); mn = lgv[h]; m[h] = mn; }
          a[h] = expf(lgv[h] - mn) * em_c;
          den[h] = den[h] * r[h] + a[h];
        }
        accv[0] = accv[0] * r[0] + a[0] * blo(vw_c.x);
        accv[1] = accv[1] * r[1] + a[1] * bhi(vw_c.x);
        accv[2] = accv[2] * r[2] + a[2] * blo(vw_c.y);
        accv[3] = accv[3] * r[3] + a[3] * bhi(vw_c.y);
        acg0 = acg0 * r[hg0] + a[hg0] * g0_c;
        if (l < 32) acg1 = acg1 * r[hg1] + a[hg1] * g1_c;
      }
      // ---- rotate pipeline registers ----
      kw_c = kw_n; zw_c = zw_n; kq1_c = kq1_n; kq2_c = kq2_n;
      vw_c = vw_n;
      g0_c = g0_n; g1_c = g1_n; em_c = em_n;
    }
  }
  // ---- write partial state ----
  if (l == 0) {
#pragma unroll
    for (int h = 0; h < 4; ++h) { MS[qtr][h] = m[h]; MS[qtr][4+h] = den[h]; }
  }
#pragma unroll
  for (int j = 0; j < 4; ++j) AV[qtr][j][l] = accv[j];
  AG0[qtr][l] = acg0;
  if (l < 32) AG1[qtr][l] = acg1;
  __syncthreads();
  if (qtr == 0) {
    // ---- merge 4 partials ----
    float rq[4][4], dC[4];
#pragma unroll
    for (int h = 0; h < 4; ++h) {
      float mC = fmaxf(fmaxf(MS[0][h], MS[1][h]), fmaxf(MS[2][h], MS[3][h]));
      dC[h] = 0.f;
#pragma unroll
      for (int q = 0; q < 4; ++q) {
        rq[q][h] = expf(MS[q][h] - mC);
        dC[h] += MS[q][4+h] * rq[q][h];
      }
    }
    float g0 = AG0[0][l]*rq[0][hg0] + AG0[1][l]*rq[1][hg0]
             + AG0[2][l]*rq[2][hg0] + AG0[3][l]*rq[3][hg0];
    OGm[l] = g0 / (dC[hg0] + 1e-9f);
    if (l < 32) {
      float g1 = AG1[0][l]*rq[0][hg1] + AG1[1][l]*rq[1][hg1]
               + AG1[2][l]*rq[2][hg1] + AG1[3][l]*rq[3][hg1];
      OGm[64 + l] = g1 / (dC[hg1] + 1e-9f);
    }
#pragma unroll
    for (int j = 0; j < 4; ++j) {
      float v = AV[0][j][l]*rq[0][j] + AV[1][j][l]*rq[1][j]
              + AV[2][j][l]*rq[2][j] + AV[3][j][l]*rq[3][j];
      catb[(size_t)n*384 + j*64 + l] = f2b(v / (dC[j] + 1e-9f));
    }
  }
  __syncthreads();
  if (qtr == 1 && l < 32) {
    // ---- olon: og -> local frame + norm (CATB cols 256..384) ----
    const float* R = rot + (size_t)n*9;
    const float* tr = trans + (size_t)n*3;
    float d0 = OGm[l*3 + 0] - tr[0];
    float d1 = OGm[l*3 + 1] - tr[1];
    float d2 = OGm[l*3 + 2] - tr[2];
    float ol0 = R[0]*d0 + R[3]*d1 + R[6]*d2;
    float ol1 = R[1]*d0 + R[4]*d1 + R[7]*d2;
    float ol2 = R[2]*d0 + R[5]*d1 + R[8]*d2;
    ushort* cp = catb + (size_t)n*384;
    cp[256 + l*3 + 0] = f2b(ol0);
    cp[256 + l*3 + 1] = f2b(ol1);
    cp[256 + l*3 + 2] = f2b(ol2);
    cp[352 + l] = f2b(sqrtf(ol0*ol0 + ol1*ol1 + ol2*ol2 + EPSF));
  }
}

__global__ void k_af_wau(float* __restrict__ af, const float* __restrict__ WauA,
                         const float* __restrict__ t1) {
  __shared__ float W[256];
  int t = threadIdx.x;
  W[t] = WauA[t];
  __syncthreads();
  int r = blockIdx.x * 256 + t;
  if (r >= NA14) return;
  int n = r / 14;
  float x[16], y[16];
#pragma unroll
  for (int j = 0; j < 16; ++j) x[j] = af[(size_t)r*16 + j];
#pragma unroll
  for (int j = 0; j < 16; ++j) y[j] = t1[(size_t)n*16 + j];
#pragma unroll
  for (int k = 0; k < 16; ++k) {
    float xv = x[k];
#pragma unroll
    for (int j = 0; j < 16; ++j) y[j] = fmaf(xv, W[k*16 + j], y[j]);
  }
  float v[16]; float s = 0.f;
#pragma unroll
  for (int j = 0; j < 16; ++j) { v[j] = x[j] + y[j]; s += v[j]; }
  float mu = s * (1.f/16.f);
  float var = 0.f;
#pragma unroll
  for (int j = 0; j < 16; ++j) { float d = v[j]-mu; var += d*d; }
  float rs = rsqrtf(var * (1.f/16.f) + 1e-5f);
#pragma unroll
  for (int j = 0; j < 16; ++j) af[(size_t)r*16 + j] = (v[j]-mu)*rs;
}

__global__ void k_af_p(float* __restrict__ af, const float* __restrict__ Wp1,
                       const float* __restrict__ Wp2, const float* __restrict__ amf) {
  __shared__ float W1[256], W2[256];
  int t = threadIdx.x;
  W1[t] = Wp1[t]; W2[t] = Wp2[t];
  __syncthreads();
  int r = blockIdx.x * 256 + t;
  if (r >= NA14) return;
  float x[16];
#pragma unroll
  for (int j = 0; j < 16; ++j) x[j] = af[(size_t)r*16 + j];
  float h1[16];
#pragma unroll
  for (int j = 0; j < 16; ++j) h1[j] = 0.f;
#pragma unroll
  for (int k = 0; k < 16; ++k) {
    float xv = x[k];
#pragma unroll
    for (int j = 0; j < 16; ++j) h1[j] = fmaf(xv, W1[k*16 + j], h1[j]);
  }
#pragma unroll
  for (int j = 0; j < 16; ++j) h1[j] = fmaxf(h1[j], 0.f);
  float h2[16];
#pragma unroll
  for (int j = 0; j < 16; ++j) h2[j] = 0.f;
#pragma unroll
  for (int k = 0; k < 16; ++k) {
    float xv = h1[k];
#pragma unroll
    for (int j = 0; j < 16; ++j) h2[j] = fmaf(xv, W2[k*16 + j], h2[j]);
  }
  float v[16]; float s = 0.f;
#pragma unroll
  for (int j = 0; j < 16; ++j) { v[j] = x[j] + h2[j]; s += v[j]; }
  float mu = s * (1.f/16.f);
  float var = 0.f;
#pragma unroll
  for (int j = 0; j < 16; ++j) { float d = v[j]-mu; var += d*d; }
  float rs = rsqrtf(var * (1.f/16.f) + 1e-5f);
  float am = amf[r];
#pragma unroll
  for (int j = 0; j < 16; ++j) af[(size_t)r*16 + j] = (v[j]-mu)*rs*am;
}

__global__ void k_sentinel(float* __restrict__ out, float val) {
  if (threadIdx.x == 0 && blockIdx.x == 0) out[0] = val;
}

// ======================= host =======================

extern "C" void kernel_launch(void* const* d_in, const int* in_sizes, int n_in,
                              void* d_out, int out_size, void* d_ws, size_t ws_size,
                              hipStream_t stream) {
  (void)in_sizes; (void)n_in; (void)out_size;
  const int*   seq    = (const int*)  d_in[0];
  const float* atom14 = (const float*)d_in[1];
  const float* rot    = (const float*)d_in[2];
  const float* trans  = (const float*)d_in[3];
  const int*   rmask  = (const int*)  d_in[4];
  const int*   mgm    = (const int*)  d_in[5];
  const int*   nmask  = (const int*)  d_in[6];
  const int*   a14ex  = (const int*)  d_in[7];
  const int*   eidx   = (const int*)  d_in[8];
  const int*   dsti   = eidx;
  const int*   srci   = eidx + EE;
  const float* atab   = (const float*)d_in[9];
  const float* Wn1 = (const float*)d_in[10];
  const float* Wn2 = (const float*)d_in[11];
  const float* Wn3 = (const float*)d_in[12];
  const float* Wez1 = (const float*)d_in[13];
  const float* Wez2 = (const float*)d_in[14];
  const float* Wez3 = (const float*)d_in[15];
  const float* Wa1 = (const float*)d_in[16];
  const float* Wa2 = (const float*)d_in[17];
  const float* Wa3 = (const float*)d_in[18];
  const float* Wq  = (const float*)d_in[19];
  const float* Wk  = (const float*)d_in[20];
  const float* Wv  = (const float*)d_in[21];
  const float* Wqp = (const float*)d_in[22];
  const float* Wkp = (const float*)d_in[23];
  const float* Wb  = (const float*)d_in[24];
  const float* gam = (const float*)d_in[25];
  const float* Wo  = (const float*)d_in[26];
  const float* Wau = (const float*)d_in[27];
  const float* Wt1 = (const float*)d_in[28];
  const float* Wt2 = (const float*)d_in[29];
  const float* Wne = (const float*)d_in[30];
  const float* We1 = (const float*)d_in[31];
  const float* We2 = (const float*)d_in[32];
  const float* Wp1 = (const float*)d_in[33];
  const float* Wp2 = (const float*)d_in[34];
  const float* Wmu = (const float*)d_in[35];
  const float* Wlv = (const float*)d_in[36];
  float* out = (float*)d_out;

  float* ws = (float*)d_ws;
  size_t WSF = ws_size / sizeof(float);
  size_t off = 0;
  auto alloc = [&](size_t n) { n = (n + 3) & ~(size_t)3; float* p = ws + off; off += n; return p; };

  // ---- persistent ----
  ushort* Zb  = (ushort*)alloc((size_t)EE * 64);
  float* S    = alloc((size_t)NR * 256);
  ushort* SB  = (ushort*)alloc((size_t)NR * 128);
  float* AF   = alloc((size_t)NA14 * 16);
  float* AMF  = alloc(NA14);
  float* EMF  = alloc(EE);
  float* RESF = alloc(NR);
  float* DP   = alloc(3 * NR);
  float* BB4  = alloc((size_t)NR * 12);
  float* BBL  = alloc((size_t)NR * 12);
  ushort* NRAWB = (ushort*)alloc((size_t)NR * 32);
  float* ARAW = alloc((size_t)NA14 * 9);
  // ---- bf16 weights ----
  ushort* WezT1 = (ushort*)alloc(45056);
  ushort* WezT2 = (ushort*)alloc(32768);
  ushort* WezT3 = (ushort*)alloc(16384);
  ushort* We1zT = (ushort*)alloc(65536);
  ushort* We1dsT = (ushort*)alloc(131072);   // 4 layers x [512][128]
  ushort* We2T  = (ushort*)alloc(65536);
  ushort* WqkvpT = (ushort*)alloc(1048576);  // 4 layers x [1024][256] (QKV|PP)
  ushort* WoT   = (ushort*)alloc(196608);
  ushort* Wt1T  = (ushort*)alloc(131072);
  ushort* Wt2T  = (ushort*)alloc(131072);
  ushort* WneT  = (ushort*)alloc(65536);
  ushort* WmuLvT= (ushort*)alloc(65536);
  ushort* Wn1T  = (ushort*)alloc(16384);
  ushort* Wn2T  = (ushort*)alloc(131072);
  ushort* Wn3T  = (ushort*)alloc(65536);
  float* WBT  = alloc(2048);
  float* COEF = alloc(16);
  // ---- node arena ----
  ushort* QKVB= (ushort*)alloc((size_t)NR * 384);
  float* PP   = alloc((size_t)NR * 256);
  float* QG   = alloc((size_t)NR * 96);
  float* KG   = alloc((size_t)NR * 96);
  ushort* CATB= (ushort*)alloc((size_t)NR * 192);
  float* NBUF = alloc((size_t)NR * 256);
  ushort* HbB = (ushort*)alloc((size_t)NR * 64);
  ushort* HDSb = (ushort*)alloc((size_t)NR * 256);   // [NR][512] bf16
  float* T1   = alloc((size_t)NR * 16);
  ushort* NB1b = (ushort*)alloc((size_t)NR * 256);
  ushort* NB2b = (ushort*)alloc((size_t)NR * 256);
  ushort* TRHb = (ushort*)alloc((size_t)NR * 128);
  float* AH1  = alloc((size_t)NA14 * 32);
  float* AH2  = alloc((size_t)NA14 * 32);
  // ---- ints ----
  int* CNT  = (int*)alloc(NR);
  int* OFFS = (int*)alloc(NR + 1);
  int* EORD = (int*)alloc(EE);
  size_t fixedF = off;

  if (fixedF + (size_t)432 * 1024 > WSF) {
    k_sentinel<<<1, 64, 0, stream>>>(out, 1.0e6f * (float)(ws_size >> 20));
    return;
  }
  float* EAR = ws + fixedF;
  size_t arenaF = WSF - fixedF;
  int CH_P = (int)((arenaF / 432 > (size_t)EE) ? (size_t)EE : arenaF / 432);
  int CH_L = (int)((arenaF / 128 > (size_t)EE) ? (size_t)EE : arenaF / 128);
  ushort* ERb = (ushort*)EAR;
  ushort* B1b = ERb + (size_t)CH_P * 352;
  ushort* B2b = B1b + (size_t)CH_P * 256;
  ushort* EARb = (ushort*)EAR;

  auto wT = [&](const float* W, ushort* WTp, int K, int N, int Kpad,
                long ss, long ds, int L, int perm, int cperm) {
    long tot = (long)N * Kpad * L;
    k_wT<<<(int)((tot + 255) / 256), 256, 0, stream>>>(W, WTp, K, N, Kpad, ss, ds, L, perm, cperm);
  };

  // ---- weight transposes (bf16) ----
  wT(Wez1, WezT1, 340, 256, 352, 0, 0, 1, 0, 0);
  wT(Wez2, WezT2, 256, 256, 256, 0, 0, 1, 1, 0);
  wT(Wez3, WezT3, 256, 128, 256, 0, 0, 1, 1, 0);
  wT(Wn1, Wn1T, 40, 512, 64, 0, 0, 1, 0, 0);
  wT(Wn2, Wn2T, 512, 512, 512, 0, 0, 1, 1, 0);
  wT(Wn3, Wn3T, 512, 256, 512, 0, 0, 1, 1, 0);
  wT(We1,         We1zT, 128, 256, 128, 98304, 32768, 4, 0, 0);
  // combined [We1_d | We1_s] -> [512][128] per layer
  wT(We1 + 32768, We1dsT,         128, 256, 128, 98304, 65536, 4, 0, 0);
  wT(We1 + 65536, We1dsT + 32768, 128, 256, 128, 98304, 65536, 4, 0, 0);
  wT(We2, We2T, 256, 128, 256, 32768, 32768, 4, 1, 0);   // A = EAR (physical perm)
  wT(Wo,  WoT,  384, 256, 384, 98304, 98304, 4, 0, 0);
  wT(Wt1, Wt1T, 256, 256, 256, 65536, 65536, 4, 0, 0);
  wT(Wt2, Wt2T, 256, 256, 256, 65536, 65536, 4, 1, 0);
  wT(Wne, WneT, 256, 128, 256, 32768, 32768, 4, 0, 0);
  wT(Wmu, WmuLvT, 256, 256, 256, 0, 0, 1, 0, 0);
  wT(Wlv, WmuLvT + 65536, 256, 256, 256, 0, 0, 1, 0, 0);
  // merged [Wq|Wk|Wv|Wqp|Wkp|pad] -> [1024][256] per layer
  wT(Wq,  WqkvpT + 0,       256, 256, 256, 65536, 262144, 4, 0, 0);
  wT(Wk,  WqkvpT + 65536,   256, 256, 256, 65536, 262144, 4, 0, 0);
  wT(Wv,  WqkvpT + 131072,  256, 256, 256, 65536, 262144, 4, 0, 1);  // V col-interleave
  wT(Wqp, WqkvpT + 196608,         256,  96, 256, 24576, 262144, 4, 0, 0);
  wT(Wkp, WqkvpT + 196608 + 24576, 256,  96, 256, 24576, 262144, 4, 0, 0);
  k_zero_us<<<(64*256*4 + 255)/256, 256, 0, stream>>>(WqkvpT + 245760, 64*256, 262144, 4);
  k_wbT<<<8, 256, 0, stream>>>(Wb, WBT);
  k_coef<<<1, 64, 0, stream>>>(gam, COEF);

  // ---- prep ----
  k_dihedral<<<(3 * NR + 255) / 256, 256, 0, stream>>>(atom14, DP);
  k_bb4<<<(NR + 255) / 256, 256, 0, stream>>>(atom14, rot, trans, rmask, BB4, BBL, RESF);
  k_noderaw<<<NR, 64, 0, stream>>>(seq, atom14, rot, trans, DP, rmask, mgm, NRAWB);
  k_atomraw<<<(NA14 + 255) / 256, 256, 0, stream>>>(seq, mgm, a14ex, atab, ARAW, AMF);

  // ---- node MLP -> s (bf16 MFMA) ----
  {
    dim3 g1((NR + 127) / 128, 4), g2((NR + 127) / 128, 4), g3((NR + 127) / 128, 2);
    k_mgemm<1,1,0,1,0,0><<<g1, 256, 0, stream>>>(NRAWB, Wn1T, nullptr, NB1b, NR, 512, 64, 64,
                                                 nullptr, nullptr, nullptr, nullptr, nullptr, 0);
    k_mgemm<1,1,0,1,0,0><<<g2, 256, 0, stream>>>(NB1b, Wn2T, nullptr, NB2b, NR, 512, 512, 512,
                                                 nullptr, nullptr, nullptr, nullptr, nullptr, 0);
    k_mgemm<0,0,0,0,0,0><<<g3, 256, 0, stream>>>(NB2b, Wn3T, NBUF, nullptr, NR, 256, 512, 512,
                                                 nullptr, nullptr, nullptr, nullptr, nullptr, 0);
  }
  k_ln<<<(NR + 3) / 4, 256, 0, stream>>>(S, SB, nullptr, NBUF, nullptr, NR);

  // ---- atom MLP -> af ----
  k_small_gemm<<<(NA14 + 7) / 8, 256, 0, stream>>>(ARAW, Wa1, AH1, NA14, 32, 9, 1);
  k_small_gemm<<<(NA14 + 7) / 8, 256, 0, stream>>>(AH1, Wa2, AH2, NA14, 32, 32, 1);
  k_small_gemm<<<(NA14 + 15) / 16, 256, 0, stream>>>(AH2, Wa3, AF, NA14, 16, 32, 0);
  k_ln16<<<(NA14 + 255) / 256, 256, 0, stream>>>(AF, NA14);

  // ---- CSR by dst ----
  k_zero_int<<<(NR + 255) / 256, 256, 0, stream>>>(CNT, NR);
  k_count<<<(EE + 255) / 256, 256, 0, stream>>>(dsti, CNT);
  k_scan<<<1, 256, 0, stream>>>(CNT, OFFS);
  k_zero_int<<<(NR + 255) / 256, 256, 0, stream>>>(CNT, NR);
  k_place<<<(EE + 255) / 256, 256, 0, stream>>>(dsti, OFFS, CNT, EORD);
  k_sortwave<<<NR, 64, 0, stream>>>(OFFS, EORD);

  // ---- edge MLP -> z (bf16 MFMA; LN fused into Wez3) ----
  for (int e0 = 0; e0 < EE; e0 += CH_P) {
    int cnt = (EE - e0 < CH_P) ? (EE - e0) : CH_P;
    k_edgeraw<<<(cnt + 3) / 4, 256, 0, stream>>>(dsti, srci, seq, rmask, nmask,
                                                 BB4, BBL, rot, trans, ERb, EMF, e0, cnt);
    dim3 g1((cnt + 127) / 128, 2), g2((cnt + 127) / 128, 2), g3((cnt + 127) / 128, 1);
    k_mgemm<1,1,0,1,0,0><<<g1, 256, 0, stream>>>(ERb, WezT1, nullptr, B1b, cnt, 256, 352, 352,
                                                 nullptr, nullptr, nullptr, nullptr, nullptr, 0);
    k_mgemm<1,1,0,1,0,0><<<g2, 256, 0, stream>>>(B1b, WezT2, nullptr, B2b, cnt, 256, 256, 256,
                                                 nullptr, nullptr, nullptr, nullptr, nullptr, 0);
    k_mgemm<0,1,0,0,1,0><<<g3, 256, 0, stream>>>(B2b, WezT3, nullptr, Zb + (size_t)e0 * 128,
                                                 cnt, 128, 256, 256,
                                                 nullptr, nullptr, nullptr, nullptr, nullptr, 0);
  }

  // ---- layers ----
  for (int l = 0; l < 4; ++l) {
    const ushort* WqkvpT_l = WqkvpT + (size_t)l * 262144;
    const ushort* WoT_l = WoT + (size_t)l * 98304;
    const float* Wau_l = Wau + (size_t)l * 4352;
    const ushort* Wt1T_l = Wt1T + (size_t)l * 65536;
    const ushort* Wt2T_l = Wt2T + (size_t)l * 65536;
    const ushort* WneT_l = WneT + (size_t)l * 32768;
    const ushort* We1zT_l = We1zT + (size_t)l * 32768;
    const ushort* We1dsT_l = We1dsT + (size_t)l * 65536;
    const ushort* We2T_l = We2T + (size_t)l * 32768;
    const float* Wp1_l = Wp1 + (size_t)l * 256;
    const float* Wp2_l = Wp2 + (size_t)l * 256;

    {
      // merged QKV (bf16 -> QKVB, cols 0..767) + PP (f32, cols 768..1023)
      dim3 gq((NR + 127) / 128, 8);
      k_mgemm<0,1,0,0,0,1><<<gq, 256, 0, stream>>>(SB, WqkvpT_l, PP, QKVB, NR, 768, 256, 256,
                                                   nullptr, nullptr, nullptr, nullptr, nullptr, 0);
    }
    k_qg<<<(NR * 64 + 255) / 256, 256, 0, stream>>>(rot, trans, PP, QG, KG);
    // fused logits + online-softmax attention + olon (1 node/block, 4 waves)
    k_attn2<<<NR, 256, 0, stream>>>(OFFS, EORD, srci, EMF, QKVB, Zb, QG, KG,
                                    WBT + (size_t)l * 512, COEF + (size_t)l * 4,
                                    rot, trans, CATB);
    {
      dim3 g((NR + 127) / 128, 2);
      k_mgemm<0,0,0,0,0,0><<<g, 256, 0, stream>>>(CATB, WoT_l, NBUF, nullptr, NR, 256, 384, 384,
                                                  nullptr, nullptr, nullptr, nullptr, nullptr, 0);
    }
    k_ln<<<(NR + 3) / 4, 256, 0, stream>>>(S, SB, S, NBUF, nullptr, NR);
    {
      dim3 g((NR + 63) / 64, 1);
      k_gemm<<<g, 256, 0, stream>>>(S, Wau_l + 256, T1, NR, 16, 256, 16, 0, 0);
    }
    k_af_wau<<<(NA14 + 255) / 256, 256, 0, stream>>>(AF, Wau_l, T1);
    {
      dim3 g((NR + 127) / 128, 2);
      k_mgemm<1,1,0,1,0,0><<<g, 256, 0, stream>>>(SB, Wt1T_l, nullptr, TRHb, NR, 256, 256, 256,
                                                  nullptr, nullptr, nullptr, nullptr, nullptr, 0);
      k_mgemm<0,0,0,0,0,0><<<g, 256, 0, stream>>>(TRHb, Wt2T_l, NBUF, nullptr, NR, 256, 256, 256,
                                                  nullptr, nullptr, nullptr, nullptr, nullptr, 0);
    }
    k_ln<<<(NR + 3) / 4, 256, 0, stream>>>(S, SB, S, NBUF, RESF, NR);
    {
      dim3 g((NR + 127) / 128, 1);
      k_mgemm<0,1,0,0,0,0><<<g, 256, 0, stream>>>(SB, WneT_l, nullptr, HbB, NR, 128, 256, 256,
                                                  nullptr, nullptr, nullptr, nullptr, nullptr, 0);
    }
    // HDS = h @ [We1_d | We1_s]  (single 512-col PERMOUT gemm)
    {
      dim3 g((NR + 127) / 128, 4);
      k_mgemm<0,1,0,1,0,0><<<g, 256, 0, stream>>>(HbB, We1dsT_l, nullptr, HDSb, NR, 512, 128, 128,
                                                  nullptr, nullptr, nullptr, nullptr, nullptr, 0);
    }
    for (int e0 = 0; e0 < EE; e0 += CH_L) {
      int cnt = (EE - e0 < CH_L) ? (EE - e0) : CH_L;
      dim3 g1((cnt + 127) / 128, 2), g2((cnt + 127) / 128, 1);
      k_mgemm<1,1,1,1,0,0><<<g1, 256, 0, stream>>>(Zb + (size_t)e0 * 128, We1zT_l, nullptr, EARb,
                                                   cnt, 256, 128, 128,
                                                   HDSb, HDSb + 256, dsti + e0, srci + e0,
                                                   nullptr, 512);
      k_mgemm<0,1,0,0,1,0><<<g2, 256, 0, stream>>>(EARb, We2T_l, nullptr, Zb + (size_t)e0 * 128,
                                                   cnt, 128, 256, 256,
                                                   nullptr, nullptr, nullptr, nullptr, EMF + e0, 0);
    }
    k_af_p<<<(NA14 + 255) / 256, 256, 0, stream>>>(AF, Wp1_l, Wp2_l, AMF);
  }

  // ---- output: fused [Wmu|Wlv] ----
  {
    dim3 g((NR + 127) / 128, 4);
    k_mgemm<0,0,0,0,0,0><<<g, 256, 0, stream>>>(SB, WmuLvT, out, nullptr, NR, 512, 256, 256,
                                                nullptr, nullptr, nullptr, nullptr, nullptr, 0);
  }
}